// Round 3
// baseline (5107.545 us; speedup 1.0000x reference)
//
#include <hip/hip_runtime.h>
#include <hip/hip_fp16.h>

#define EMB   32
#define HID   256
#define BATCH 64
#define TT    2048

typedef _Float16 half2_t __attribute__((ext_vector_type(2)));
typedef _Float16 half8_t __attribute__((ext_vector_type(8)));

// ---- ws regions (bytes) ----
// WV : VGPR-resident weights, [t in 0..512)][r in 0..5)][jj in 0..9)] half8
// WL : LDS-resident weights,  [r2 in 0..2)][jj in 0..9)][t in 0..512)] half8 (lane-consecutive)
// WS : streamed weights,      [jj in 0..9)][t in 0..512)] half8 (lane-consecutive)
// B  : combined bias,         [q in 0..128)][r in 0..8) float
#define WV_OFF 0          // 512*45*16 = 368640
#define WL_OFF 368640     // 2*9*512*16 = 147456
#define WS_OFF 516096     // 9*512*16 = 73728
#define B_OFF  589824     // 4096  -> total 593920

// ---- dynamic LDS ----
#define LDS_XH0  147456   // weight image [0,147456)
#define LDS_XH1  148096   // xh buffers: 320 halves each (288 used), 16B aligned
#define LDS_TOTAL 148736

// Thread t: quartet q = t>>2 owns h-indices h0=q, h1=q+128.
// Lane l = t&3 owns cols [72l, 72l+72).
// Row classes r: 0=i(h0) 1=f(h0) 2=g(h0) 3=o(h0) 4=i(h1) [VGPR]
//               5=f(h1) 6=g(h1) [LDS]   7=o(h1) [streamed]
__device__ __forceinline__ int row_of(int q, int r) {
    switch (r) {
        case 0: return q;          // i, h0
        case 1: return 256 + q;    // f, h0
        case 2: return 512 + q;    // g, h0
        case 3: return 768 + q;    // o, h0
        case 4: return 128 + q;    // i, h1
        case 5: return 384 + q;    // f, h1
        case 6: return 640 + q;    // g, h1
        default: return 896 + q;   // o, h1
    }
}

__device__ __forceinline__ float wval(const float* __restrict__ W_ih,
                                      const float* __restrict__ W_hh,
                                      int row, int col) {
    return (col < EMB) ? W_ih[row * EMB + col] : W_hh[row * HID + (col - EMB)];
}

__device__ __forceinline__ float fdot2(half2_t a, half2_t b, float c) {
#if __has_builtin(__builtin_amdgcn_fdot2)
    return __builtin_amdgcn_fdot2(a, b, c, false);
#else
    return c + (float)a[0] * (float)b[0] + (float)a[1] * (float)b[1];
#endif
}

__device__ __forceinline__ float dot8(half8_t w, half8_t x, float acc) {
    acc = fdot2(half2_t{w[0], w[1]}, half2_t{x[0], x[1]}, acc);
    acc = fdot2(half2_t{w[2], w[3]}, half2_t{x[2], x[3]}, acc);
    acc = fdot2(half2_t{w[4], w[5]}, half2_t{x[4], x[5]}, acc);
    acc = fdot2(half2_t{w[6], w[7]}, half2_t{x[6], x[7]}, acc);
    return acc;
}

__device__ __forceinline__ float sigmoid_fast(float v) {
    return 1.0f / (1.0f + __expf(-v));
}
__device__ __forceinline__ float tanh_fast(float v) {
    v = fminf(fmaxf(v, -20.0f), 20.0f);
    float e = __expf(2.0f * v);
    return (e - 1.0f) / (e + 1.0f);
}

// ---- prep: scatter fp32 weights into fp16 WV/WL/WS layouts, combine biases ----
// 145 blocks x 256 threads. items: WV 23040 half8, WL 9216, WS 4608, bias 1024.
__global__ void prep_kernel(const float* __restrict__ W_ih,
                            const float* __restrict__ W_hh,
                            const float* __restrict__ b_ih,
                            const float* __restrict__ b_hh,
                            char* __restrict__ ws) {
    int bid = blockIdx.x, tid = threadIdx.x;
    int gid = bid * 256 + tid;
    if (bid < 90) {                              // WV: gid in [0,23040)
        int t = gid / 45, rem = gid % 45;
        int r = rem / 9, jj = rem % 9;
        int q = t >> 2, l = t & 3;
        int row = row_of(q, r);
        int cb = 72 * l + 8 * jj;
        half8_t v;
#pragma unroll
        for (int e = 0; e < 8; ++e) v[e] = (_Float16)wval(W_ih, W_hh, row, cb + e);
        *(half8_t*)(ws + WV_OFF + (size_t)gid * 16) = v;   // (t*45 + r*9 + jj) == gid
    } else if (bid < 126) {                      // WL: idx in [0,9216)
        int idx = gid - 23040;
        int r2 = idx / 4608, rem = idx % 4608;
        int jj = rem / 512, t = rem % 512;
        int q = t >> 2, l = t & 3;
        int row = row_of(q, 5 + r2);
        int cb = 72 * l + 8 * jj;
        half8_t v;
#pragma unroll
        for (int e = 0; e < 8; ++e) v[e] = (_Float16)wval(W_ih, W_hh, row, cb + e);
        *(half8_t*)(ws + WL_OFF + (size_t)idx * 16) = v;   // (r2*9+jj)*512 + t == idx
    } else if (bid < 144) {                      // WS: idx in [0,4608)
        int idx = gid - 32256;
        int jj = idx / 512, t = idx % 512;
        int q = t >> 2, l = t & 3;
        int row = row_of(q, 7);
        int cb = 72 * l + 8 * jj;
        half8_t v;
#pragma unroll
        for (int e = 0; e < 8; ++e) v[e] = (_Float16)wval(W_ih, W_hh, row, cb + e);
        *(half8_t*)(ws + WS_OFF + (size_t)idx * 16) = v;   // jj*512 + t == idx
    } else {                                     // bias
        for (int i = tid; i < 1024; i += 256) {
            int q = i >> 3, r = i & 7;
            int row = row_of(q, r);
            ((float*)(ws + B_OFF))[i] = b_ih[row] + b_hh[row];
        }
    }
}

// ---- recurrent kernel: one block (512 thr, 8 waves) per batch element ----
__global__ __launch_bounds__(512, 2) void rnn_kernel(const int* __restrict__ x,
                                                     const int* __restrict__ lengths,
                                                     const float* __restrict__ emb,
                                                     const char* __restrict__ ws,
                                                     float* __restrict__ out) {
    extern __shared__ char smem[];
    const half8_t* __restrict__ wl = (const half8_t*)smem;
    _Float16* xh0 = (_Float16*)(smem + LDS_XH0);
    _Float16* xh1 = (_Float16*)(smem + LDS_XH1);

    const int b   = blockIdx.x;
    const int tid = threadIdx.x;
    const int q   = tid >> 2;
    const int l   = tid & 3;

    // stage LDS weight image (one-time): 9216 uint4, lane-consecutive
    {
        const uint4* src = (const uint4*)(ws + WL_OFF);
        uint4*       dst = (uint4*)smem;
#pragma unroll
        for (int k = 0; k < 18; ++k) dst[tid + k * 512] = src[tid + k * 512];
    }

    // VGPR-resident weights: 5 rows x 9 chunks = 180 VGPRs
    half8_t wv[5][9];
    {
        const half8_t* WVp = (const half8_t*)(ws + WV_OFF) + (size_t)tid * 45;
#pragma unroll
        for (int r = 0; r < 5; ++r)
#pragma unroll
            for (int jj = 0; jj < 9; ++jj) wv[r][jj] = WVp[r * 9 + jj];
    }

    // biases for the quartet's 8 rows (replicated across the 4 lanes)
    float bs[8];
    {
        const float* bp = (const float*)(ws + B_OFF) + q * 8;
#pragma unroll
        for (int r = 0; r < 8; ++r) bs[r] = bp[r];
    }

    int L = lengths[b];
    if (L > TT) L = TT;
    if (L < 0) L = 0;
    const int* __restrict__ xb = x + b * TT;

    // init xh0: x-part = emb[token 0], h-part = 0
    if (tid < HID) xh0[EMB + tid] = (_Float16)0.0f;
    if (tid < EMB && L > 0) xh0[tid] = (_Float16)emb[xb[0] * EMB + tid];
    __syncthreads();

    const half8_t* __restrict__ Wside = (const half8_t*)(ws + WS_OFF);

    float c0 = 0.f, c1 = 0.f, h0s = 0.f, h1s = 0.f;
    int par = 0;

#pragma unroll 1
    for (int ts = 0; ts < L; ++ts) {
        _Float16* cur = par ? xh1 : xh0;
        _Float16* nxt = par ? xh0 : xh1;

        // prefetch next token's embedding early (long latency)
        float ev = 0.0f;
        if (tid < EMB) {
            int nt = (ts + 1 < L) ? xb[ts + 1] : 0;
            ev = emb[nt * EMB + tid];
        }

        // issue streamed o(h1) row loads (L2-resident 72 KB region)
        half8_t sw[9];
#pragma unroll
        for (int jj = 0; jj < 9; ++jj) sw[jj] = Wside[jj * 512 + tid];

        float a0 = 0.f, a1 = 0.f, a2 = 0.f, a3 = 0.f;
        float a4 = 0.f, a5 = 0.f, a6 = 0.f, a7 = 0.f;

#pragma unroll
        for (int jj = 0; jj < 9; ++jj) {
            half8_t xv = *(const half8_t*)(cur + 72 * l + 8 * jj);  // 4-addr multicast
            a0 = dot8(wv[0][jj], xv, a0);
            a1 = dot8(wv[1][jj], xv, a1);
            a2 = dot8(wv[2][jj], xv, a2);
            a3 = dot8(wv[3][jj], xv, a3);
            a4 = dot8(wv[4][jj], xv, a4);
            a5 = dot8(wl[jj * 512 + tid], xv, a5);          // f(h1)
            a6 = dot8(wl[(9 + jj) * 512 + tid], xv, a6);    // g(h1)
            a7 = dot8(sw[jj], xv, a7);                      // o(h1)
        }

        // quartet butterfly reduce (bitwise-identical on all 4 lanes)
        a0 += __shfl_xor(a0, 1); a0 += __shfl_xor(a0, 2);
        a1 += __shfl_xor(a1, 1); a1 += __shfl_xor(a1, 2);
        a2 += __shfl_xor(a2, 1); a2 += __shfl_xor(a2, 2);
        a3 += __shfl_xor(a3, 1); a3 += __shfl_xor(a3, 2);
        a4 += __shfl_xor(a4, 1); a4 += __shfl_xor(a4, 2);
        a5 += __shfl_xor(a5, 1); a5 += __shfl_xor(a5, 2);
        a6 += __shfl_xor(a6, 1); a6 += __shfl_xor(a6, 2);
        a7 += __shfl_xor(a7, 1); a7 += __shfl_xor(a7, 2);

        float i0 = sigmoid_fast(a0 + bs[0]);
        float f0 = sigmoid_fast(a1 + bs[1]);
        float g0 = tanh_fast(a2 + bs[2]);
        float o0 = sigmoid_fast(a3 + bs[3]);
        c0 = f0 * c0 + i0 * g0;
        h0s = o0 * tanh_fast(c0);

        float i1 = sigmoid_fast(a4 + bs[4]);
        float f1 = sigmoid_fast(a5 + bs[5]);
        float g1 = tanh_fast(a6 + bs[6]);
        float o1 = sigmoid_fast(a7 + bs[7]);
        c1 = f1 * c1 + i1 * g1;
        h1s = o1 * tanh_fast(c1);

        if (l == 0) {
            nxt[EMB + q]       = (_Float16)h0s;   // h[q]
            nxt[EMB + 128 + q] = (_Float16)h1s;   // h[q+128]
        }
        if (tid < EMB) nxt[tid] = (_Float16)ev;   // x-part for step ts+1

        __syncthreads();
        par ^= 1;
    }

    if (l == 0) {
        out[b * HID + q]       = h0s;
        out[b * HID + 128 + q] = h1s;
    }
}

extern "C" void kernel_launch(void* const* d_in, const int* in_sizes, int n_in,
                              void* d_out, int out_size, void* d_ws, size_t ws_size,
                              hipStream_t stream) {
    const int*   x       = (const int*)d_in[0];
    const int*   lengths = (const int*)d_in[1];
    const float* emb     = (const float*)d_in[2];
    const float* W_ih    = (const float*)d_in[3];
    const float* W_hh    = (const float*)d_in[4];
    const float* b_ih    = (const float*)d_in[5];
    const float* b_hh    = (const float*)d_in[6];
    float* out = (float*)d_out;
    char*  ws  = (char*)d_ws;

    hipFuncSetAttribute(reinterpret_cast<const void*>(rnn_kernel),
                        hipFuncAttributeMaxDynamicSharedMemorySize, LDS_TOTAL);

    prep_kernel<<<145, 256, 0, stream>>>(W_ih, W_hh, b_ih, b_hh, ws);
    rnn_kernel<<<BATCH, 512, LDS_TOTAL, stream>>>(x, lengths, emb, ws, out);
}

// Round 4
// 3196.052 us; speedup vs baseline: 1.5981x; 1.5981x over previous
//
#include <hip/hip_runtime.h>
#include <hip/hip_fp16.h>

#define EMB 32
#define HID 256
#define BATCH 64
#define TT  2048

typedef _Float16 half8_t __attribute__((ext_vector_type(8)));
typedef _Float16 half2_t __attribute__((ext_vector_type(2)));

// ---- d_ws layout ----
// W    : [role 2][chunk 36][tid 512] half8   (589,824 B)  weight fragments
//        role R block, thread t (q=t>>2, l=t&3), chunk c=r*9+jj:
//        gate r of h-index Q=128R+q, slice-l columns p=8*jj+e
// BIAS : [Q 256][r 4] float (4 KB)
// ACK  : int[128] end-of-loop handshake
#define W_BYTES  (2*36*512*16)
#define BIAS_OFF W_BYTES
#define ACK_OFF  (BIAS_OFF + 4096)

// ---- d_out doubles as the h-exchange region during the loop ----
// chain b: dwords [b*256, b*256+256):
//   A: slot0 [0,64) slot1 [64,128) ; B: slot0 [128,192) slot1 [192,256)
// h(k) goes to slot k&1, each half carries tag ((k>>1)&1) in bit0.
// prep zero-inits: slot0 dwords = 0x00000000 (tag0), slot1 = 0x00010001 (tag1),
// so first-use tags (slot1: h(1) tag0; slot0: h(2) tag1) never false-match.

__device__ __forceinline__ float fdot2(half2_t a, half2_t b, float c) {
#if __has_builtin(__builtin_amdgcn_fdot2)
    return __builtin_amdgcn_fdot2(a, b, c, false);
#else
    return c + (float)a[0] * (float)b[0] + (float)a[1] * (float)b[1];
#endif
}

__device__ __forceinline__ float dot8(half8_t w, half8_t x, float acc) {
    acc = fdot2(half2_t{w[0], w[1]}, half2_t{x[0], x[1]}, acc);
    acc = fdot2(half2_t{w[2], w[3]}, half2_t{x[2], x[3]}, acc);
    acc = fdot2(half2_t{w[4], w[5]}, half2_t{x[4], x[5]}, acc);
    acc = fdot2(half2_t{w[6], w[7]}, half2_t{x[6], x[7]}, acc);
    return acc;
}

__device__ __forceinline__ float sigmoid_fast(float v) {
    return 1.0f / (1.0f + __expf(-v));
}
__device__ __forceinline__ float tanh_fast(float v) {
    v = fminf(fmaxf(v, -20.0f), 20.0f);
    float e = __expf(2.0f * v);
    return (e - 1.0f) / (e + 1.0f);
}

// quartet sum via DPP quad_perm (VALU pipe, not LDS): all 4 lanes get the total
__device__ __forceinline__ float quad_reduce(float v) {
    int t = __builtin_amdgcn_mov_dpp(__float_as_int(v), 0xB1, 0xF, 0xF, true); // [1,0,3,2]
    v += __int_as_float(t);
    t = __builtin_amdgcn_mov_dpp(__float_as_int(v), 0x4E, 0xF, 0xF, true);     // [2,3,0,1]
    v += __int_as_float(t);
    return v;
}

__device__ __forceinline__ int gate_row(int r, int Q) {
    return r == 0 ? Q : r == 1 ? 256 + Q : r == 2 ? 512 + Q : 768 + Q;
}

// ---- prep: weight fragments, bias, d_out exchange init ----
// grid 105 x 512: blocks 0..71 weights (R=bid/36, c=bid%36); 72 bias; 73..104 d_out init
__global__ void prep_kernel(const float* __restrict__ W_ih,
                            const float* __restrict__ W_hh,
                            const float* __restrict__ b_ih,
                            const float* __restrict__ b_hh,
                            char* __restrict__ ws,
                            unsigned int* __restrict__ outw) {
    int bid = blockIdx.x, t = threadIdx.x;
    if (bid < 72) {
        int R = bid / 36, c = bid % 36;
        int r = c / 9, jj = c % 9;
        int Q = 128 * R + (t >> 2), l = t & 3;
        int row = gate_row(r, Q);
        half8_t v;
#pragma unroll
        for (int e = 0; e < 8; ++e) {
            int p = 8 * jj + e;
            float f;
            if (p < 8)       f = W_ih[row * EMB + 8 * l + p];
            else if (p < 40) f = W_hh[row * HID + 128 * R + 32 * l + (p - 8)];
            else             f = W_hh[row * HID + 128 * (1 - R) + 32 * l + (p - 40)];
            v[e] = (_Float16)f;
        }
        ((half8_t*)ws)[((size_t)bid) * 512 + t] = v;   // (R*36+c)*512 + t
    } else if (bid == 72) {
        float* bias = (float*)(ws + BIAS_OFF);
        for (int i = t; i < 1024; i += 512) {
            int Q = i >> 2, r = i & 3;
            int row = gate_row(r, Q);
            bias[i] = b_ih[row] + b_hh[row];
        }
    } else {
        int g = (bid - 73) * 512 + t;                  // [0, 16384)
        unsigned int val = ((g >> 6) & 1) ? 0x00010001u : 0u;
        outw[g] = val;
    }
}

// ---- recurrent kernel: 128 blocks (2 per chain), 512 threads ----
// block bid: role = bid>>6 (0: h[0:128), 1: h[128:256)), chain b = bid&63.
// pair (i, i+64) lands on the same XCD under round-robin dispatch (perf heuristic).
// thread t: quartet q=t>>2 owns h-index Q=128*role+q; lane l=t&3 owns 72 cols.
// xh slice layout (per l, 72 halves): [x 8][own-h 32][partner-h 32].
__global__ __launch_bounds__(512, 2) void rnn_kernel(const int* __restrict__ x,
                                                     const int* __restrict__ lengths,
                                                     const float* __restrict__ emb,
                                                     char* __restrict__ ws,
                                                     float* __restrict__ out_) {
    __shared__ __align__(16) _Float16 xhbuf[2][320];

    const int bid  = blockIdx.x;
    const int role = bid >> 6;
    const int b    = bid & 63;
    const int tid  = threadIdx.x;
    const int q    = tid >> 2;
    const int l    = tid & 3;
    const int Q    = 128 * role + q;

    // register-resident weights: 4 gates x 9 chunks = 144 VGPRs
    half8_t w[4][9];
    {
        const half8_t* Wp = (const half8_t*)ws + (size_t)role * 36 * 512;
#pragma unroll
        for (int r = 0; r < 4; ++r)
#pragma unroll
            for (int jj = 0; jj < 9; ++jj) w[r][jj] = Wp[(r * 9 + jj) * 512 + tid];
    }
    float4 bs = *(const float4*)(ws + BIAS_OFF + (size_t)Q * 16);

    unsigned int* exch = (unsigned int*)out_ + (size_t)b * 256;
    unsigned int* mine = exch + role * 128;          // my data slots (2 x 64 dwords)
    unsigned int* part = exch + (1 - role) * 128;    // partner's

    int L = lengths[b];
    if (L > TT) L = TT;
    if (L < 1) L = 1;
    const int* __restrict__ xb = x + b * TT;

    // init xh[0]: zeros then x(0)
    if (tid < 320) xhbuf[0][tid] = (_Float16)0.0f;
    __syncthreads();
    if (tid < EMB) {
        float e0 = emb[xb[0] * EMB + tid];
        xhbuf[0][72 * (tid >> 3) + (tid & 7)] = (_Float16)e0;
    }
    __syncthreads();

    float cc = 0.0f, hh = 0.0f;

#pragma unroll 1
    for (int t = 0; t < L; ++t) {
        const _Float16* __restrict__ cur = xhbuf[t & 1];
        _Float16* __restrict__ nxt = xhbuf[(t + 1) & 1];

        // x(t+1) embedding prefetch (wave1 lanes 0-31)
        float ev = 0.0f;
        if (tid >= 64 && tid < 64 + EMB) {
            int nt = (t + 1 < L) ? xb[t + 1] : 0;
            ev = emb[nt * EMB + (tid - 64)];
        }

        // dots: 4 gate rows x 72 cols (this lane's K-slice)
        float a0 = 0.f, a1 = 0.f, a2 = 0.f, a3 = 0.f;
#pragma unroll
        for (int jj = 0; jj < 9; ++jj) {
            half8_t xv = *(const half8_t*)(cur + 72 * l + 8 * jj);
            a0 = dot8(w[0][jj], xv, a0);
            a1 = dot8(w[1][jj], xv, a1);
            a2 = dot8(w[2][jj], xv, a2);
            a3 = dot8(w[3][jj], xv, a3);
        }
        // K-reduce across the quartet (all 4 lanes end with full sums)
        a0 = quad_reduce(a0);
        a1 = quad_reduce(a1);
        a2 = quad_reduce(a2);
        a3 = quad_reduce(a3);

        float iv = sigmoid_fast(a0 + bs.x);
        float fv = sigmoid_fast(a1 + bs.y);
        float gv = tanh_fast(a2 + bs.z);
        float ov = sigmoid_fast(a3 + bs.w);
        cc = fv * cc + iv * gv;
        hh = ov * tanh_fast(cc);

        const unsigned int tg = ((unsigned)(t + 1) >> 1) & 1u;
        const int p1 = (t + 1) & 1;

        // publish own h(t+1): fp16 with tag in bit0, paired into dwords
        _Float16 hf = (_Float16)hh;
        unsigned short hb = __builtin_bit_cast(unsigned short, hf);
        unsigned int tb = (unsigned int)((hb & 0xFFFEu) | tg);
        unsigned int nb = (unsigned int)__builtin_amdgcn_mov_dpp((int)tb, 0x104, 0xF, 0xF, true); // lane i <- i+4
        if ((tid & 7) == 0) {
            unsigned int dw = tb | (nb << 16);
            __hip_atomic_store(mine + p1 * 64 + (tid >> 3), dw,
                               __ATOMIC_RELAXED, __HIP_MEMORY_SCOPE_AGENT);
        }
        // own h -> LDS next buffer (full precision)
        if (l == 0) nxt[72 * (q >> 5) + 8 + (q & 31)] = hf;
        // x(t+1) -> LDS next buffer
        if (tid >= 64 && tid < 64 + EMB) {
            int k = tid - 64;
            nxt[72 * (k >> 3) + (k & 7)] = (_Float16)ev;
        }
        // wave0: spin for partner h(t+1) (tag check = freshness) and copy to LDS
        if (tid < 64) {
            const unsigned int* ps = part + p1 * 64;
            unsigned int dw = 0;
            int tries = 0;
            while (true) {
                dw = __hip_atomic_load(ps + tid, __ATOMIC_RELAXED, __HIP_MEMORY_SCOPE_AGENT);
                int ok = ((dw & 1u) == tg) && (((dw >> 16) & 1u) == tg);
                if (__all(ok)) break;
                if (++tries > (1 << 20)) break;   // bounded: fail loud, not hung
                __builtin_amdgcn_s_sleep(2);
            }
            unsigned short p0 = (unsigned short)(dw & 0xFFFEu);
            unsigned short p1h = (unsigned short)((dw >> 16) & 0xFFFEu);
            int j0 = 2 * tid, j1 = 2 * tid + 1;
            nxt[72 * (j0 >> 5) + 40 + (j0 & 31)] = __builtin_bit_cast(_Float16, p0);
            nxt[72 * (j1 >> 5) + 40 + (j1 & 31)] = __builtin_bit_cast(_Float16, p1h);
        }
        __syncthreads();
    }

    // end handshake (d_ws): partner done reading my d_out region -> safe to write output
    int* ack = (int*)(ws + ACK_OFF);
    if (tid == 0)
        __hip_atomic_store(&ack[bid], L, __ATOMIC_RELEASE, __HIP_MEMORY_SCOPE_AGENT);
    if (tid == 0) {
        int tries = 0;
        while (__hip_atomic_load(&ack[bid ^ 64], __ATOMIC_ACQUIRE, __HIP_MEMORY_SCOPE_AGENT) != L) {
            if (++tries > (1 << 20)) break;
            __builtin_amdgcn_s_sleep(8);
        }
    }
    __syncthreads();
    if (l == 0) out_[(size_t)b * 256 + 128 * role + q] = hh;
}

extern "C" void kernel_launch(void* const* d_in, const int* in_sizes, int n_in,
                              void* d_out, int out_size, void* d_ws, size_t ws_size,
                              hipStream_t stream) {
    const int*   x       = (const int*)d_in[0];
    const int*   lengths = (const int*)d_in[1];
    const float* emb     = (const float*)d_in[2];
    const float* W_ih    = (const float*)d_in[3];
    const float* W_hh    = (const float*)d_in[4];
    const float* b_ih    = (const float*)d_in[5];
    const float* b_hh    = (const float*)d_in[6];

    prep_kernel<<<105, 512, 0, stream>>>(W_ih, W_hh, b_ih, b_hh,
                                         (char*)d_ws, (unsigned int*)d_out);
    rnn_kernel<<<128, 512, 0, stream>>>(x, lengths, emb, (char*)d_ws, (float*)d_out);
}

// Round 5
// 2535.333 us; speedup vs baseline: 2.0145x; 1.2606x over previous
//
#include <hip/hip_runtime.h>
#include <hip/hip_fp16.h>

#define EMB 32
#define HID 256
#define BATCH 64
#define TT  2048

typedef _Float16 half8_t __attribute__((ext_vector_type(8)));
typedef _Float16 half2_t __attribute__((ext_vector_type(2)));

// ---- d_ws layout ----
// W    : [role 2][chunk 36][tid 512] half8   (589,824 B)
//        chunk c=r*9+jj: gate r of h-index Q=128R+(t>>2), lane l=t&3 cols p=8jj+e:
//        p<8 -> x (W_ih col 8l+p); p in [8,40) -> own-h (W_hh 128R+32l+p-8);
//        p in [40,72) -> partner-h (W_hh 128(1-R)+32l+p-40)
// BIAS : [Q 256][r 4] float
// ACK  : int[128]
#define W_BYTES  (2*36*512*16)
#define BIAS_OFF W_BYTES
#define ACK_OFF  (BIAS_OFF + 4096)

// ---- d_out doubles as h-exchange during the loop (same protocol as R4) ----
// chain b dwords [b*256, b*256+256): role R data at +128R, slot k&1 (64 dw each);
// each half carries tag ((k>>1)&1) in bit0. prep inits slot0=tag0, slot1=tag1.

__device__ __forceinline__ float fdot2(half2_t a, half2_t b, float c) {
#if __has_builtin(__builtin_amdgcn_fdot2)
    return __builtin_amdgcn_fdot2(a, b, c, false);
#else
    return c + (float)a[0] * (float)b[0] + (float)a[1] * (float)b[1];
#endif
}

__device__ __forceinline__ float dot8(half8_t w, half8_t x, float acc) {
    acc = fdot2(half2_t{w[0], w[1]}, half2_t{x[0], x[1]}, acc);
    acc = fdot2(half2_t{w[2], w[3]}, half2_t{x[2], x[3]}, acc);
    acc = fdot2(half2_t{w[4], w[5]}, half2_t{x[4], x[5]}, acc);
    acc = fdot2(half2_t{w[6], w[7]}, half2_t{x[6], x[7]}, acc);
    return acc;
}

__device__ __forceinline__ float rcp_fast(float v) {
#if __has_builtin(__builtin_amdgcn_rcpf)
    return __builtin_amdgcn_rcpf(v);
#else
    return 1.0f / v;
#endif
}
__device__ __forceinline__ float sigmoid_fast(float v) {
    return rcp_fast(1.0f + __expf(-v));
}
__device__ __forceinline__ float tanh_fast(float v) {
    v = fminf(fmaxf(v, -15.0f), 15.0f);
    float e = __expf(2.0f * v);
    return (e - 1.0f) * rcp_fast(e + 1.0f);
}

// LDS-only barrier: wait local DS ops, then s_barrier. No vmcnt drain, so
// MALL-bound publish stores / poll loads stay in flight across it.
__device__ __forceinline__ void barrier_lds() {
    asm volatile("s_waitcnt lgkmcnt(0)\n\ts_barrier" ::: "memory");
}

// quartet sum via DPP quad_perm (VALU pipe): all 4 lanes get the total
__device__ __forceinline__ float quad_reduce(float v) {
    int t = __builtin_amdgcn_mov_dpp(__float_as_int(v), 0xB1, 0xF, 0xF, true);
    v += __int_as_float(t);
    t = __builtin_amdgcn_mov_dpp(__float_as_int(v), 0x4E, 0xF, 0xF, true);
    v += __int_as_float(t);
    return v;
}

__device__ __forceinline__ int gate_row(int r, int Q) {
    return r == 0 ? Q : r == 1 ? 256 + Q : r == 2 ? 512 + Q : 768 + Q;
}

// ---- prep (identical layout to R4) ----
__global__ void prep_kernel(const float* __restrict__ W_ih,
                            const float* __restrict__ W_hh,
                            const float* __restrict__ b_ih,
                            const float* __restrict__ b_hh,
                            char* __restrict__ ws,
                            unsigned int* __restrict__ outw) {
    int bid = blockIdx.x, t = threadIdx.x;
    if (bid < 72) {
        int R = bid / 36, c = bid % 36;
        int r = c / 9, jj = c % 9;
        int Q = 128 * R + (t >> 2), l = t & 3;
        int row = gate_row(r, Q);
        half8_t v;
#pragma unroll
        for (int e = 0; e < 8; ++e) {
            int p = 8 * jj + e;
            float f;
            if (p < 8)       f = W_ih[row * EMB + 8 * l + p];
            else if (p < 40) f = W_hh[row * HID + 128 * R + 32 * l + (p - 8)];
            else             f = W_hh[row * HID + 128 * (1 - R) + 32 * l + (p - 40)];
            v[e] = (_Float16)f;
        }
        ((half8_t*)ws)[((size_t)bid) * 512 + t] = v;
    } else if (bid == 72) {
        float* bias = (float*)(ws + BIAS_OFF);
        for (int i = t; i < 1024; i += 512) {
            int Q = i >> 2, r = i & 3;
            int row = gate_row(r, Q);
            bias[i] = b_ih[row] + b_hh[row];
        }
    } else {
        int g = (bid - 73) * 512 + t;
        unsigned int val = ((g >> 6) & 1) ? 0x00010001u : 0u;
        outw[g] = val;
    }
}

// ---- recurrent kernel: 128 blocks (2 per chain), 512 threads ----
// Loop is software-pipelined: own+x partial dots (jj 0..4) for step t+1 run at
// the tail of iteration t, in the shadow of the cross-CU h-exchange flight.
__global__ __launch_bounds__(512, 2) void rnn_kernel(const int* __restrict__ x,
                                                     const int* __restrict__ lengths,
                                                     const float* __restrict__ emb,
                                                     char* __restrict__ ws,
                                                     float* __restrict__ out_) {
    __shared__ __align__(16) _Float16 xhbuf[2][320];

    const int bid  = blockIdx.x;
    const int role = bid >> 6;
    const int b    = bid & 63;
    const int tid  = threadIdx.x;
    const int q    = tid >> 2;
    const int l    = tid & 3;
    const int Q    = 128 * role + q;

    // register-resident weights: 4 gates x 9 chunks
    half8_t w[4][9];
    {
        const half8_t* Wp = (const half8_t*)ws + (size_t)role * 36 * 512;
#pragma unroll
        for (int r = 0; r < 4; ++r)
#pragma unroll
            for (int jj = 0; jj < 9; ++jj) w[r][jj] = Wp[(r * 9 + jj) * 512 + tid];
    }
    float4 bs = *(const float4*)(ws + BIAS_OFF + (size_t)Q * 16);

    unsigned int* exch = (unsigned int*)out_ + (size_t)b * 256;
    unsigned int* mine = exch + role * 128;
    unsigned int* part = exch + (1 - role) * 128;

    int L = lengths[b];
    if (L > TT) L = TT;
    if (L < 1) L = 1;
    const int* __restrict__ xb = x + b * TT;

    // init buf0: zeros, then x(0)
    if (tid < 320) xhbuf[0][tid] = (_Float16)0.0f;
    __syncthreads();
    if (tid < EMB) {
        float e0 = emb[xb[0] * EMB + tid];
        xhbuf[0][72 * (tid >> 3) + (tid & 7)] = (_Float16)e0;
    }
    __syncthreads();

    float cc = 0.0f, hh = 0.0f;

    // prologue: own+x partials for step 0 (own-h(0)=0 contributes nothing, but
    // the code path is uniform)
    float p0 = 0.f, p1 = 0.f, p2 = 0.f, p3 = 0.f;
    {
        const _Float16* cur = xhbuf[0];
        half8_t xv[5];
#pragma unroll
        for (int jj = 0; jj < 5; ++jj) xv[jj] = *(const half8_t*)(cur + 72 * l + 8 * jj);
#pragma unroll
        for (int jj = 0; jj < 5; ++jj) {
            p0 = dot8(w[0][jj], xv[jj], p0);
            p1 = dot8(w[1][jj], xv[jj], p1);
            p2 = dot8(w[2][jj], xv[jj], p2);
            p3 = dot8(w[3][jj], xv[jj], p3);
        }
    }

#pragma unroll 1
    for (int t = 0; t < L; ++t) {
        const _Float16* __restrict__ cur = xhbuf[t & 1];
        _Float16* __restrict__ nxt = xhbuf[(t + 1) & 1];

        // x(t+1) embedding prefetch (wave1 lanes 0-31) — consumed pre-barrier-A
        float ev = 0.0f;
        if (tid >= 64 && tid < 64 + EMB) {
            int nt = (t + 1 < L) ? xb[t + 1] : 0;
            ev = emb[nt * EMB + (tid - 64)];
        }

        // 1. partner-col dots (jj 5..8) complete the gate pre-activations
        float a0 = p0, a1 = p1, a2 = p2, a3 = p3;
        {
            half8_t xv[4];
#pragma unroll
            for (int jj = 0; jj < 4; ++jj)
                xv[jj] = *(const half8_t*)(cur + 72 * l + 40 + 8 * jj);
#pragma unroll
            for (int jj = 0; jj < 4; ++jj) {
                a0 = dot8(w[0][5 + jj], xv[jj], a0);
                a1 = dot8(w[1][5 + jj], xv[jj], a1);
                a2 = dot8(w[2][5 + jj], xv[jj], a2);
                a3 = dot8(w[3][5 + jj], xv[jj], a3);
            }
        }

        // 2. reduce + activations
        a0 = quad_reduce(a0);
        a1 = quad_reduce(a1);
        a2 = quad_reduce(a2);
        a3 = quad_reduce(a3);
        float iv = sigmoid_fast(a0 + bs.x);
        float fv = sigmoid_fast(a1 + bs.y);
        float gv = tanh_fast(a2 + bs.z);
        float ov = sigmoid_fast(a3 + bs.w);
        cc = fv * cc + iv * gv;
        hh = ov * tanh_fast(cc);

        const unsigned int tg = ((unsigned)(t + 1) >> 1) & 1u;
        const int ps_ = (t + 1) & 1;

        // 3. publish own h(t+1) (store stays in flight across the raw barriers)
        _Float16 hf = (_Float16)hh;
        unsigned short hb = __builtin_bit_cast(unsigned short, hf);
        unsigned int tb = (unsigned int)((hb & 0xFFFEu) | tg);
        unsigned int nb = (unsigned int)__builtin_amdgcn_mov_dpp((int)tb, 0x104, 0xF, 0xF, true);
        if ((tid & 7) == 0) {
            unsigned int dw = tb | (nb << 16);
            __hip_atomic_store(mine + ps_ * 64 + (tid >> 3), dw,
                               __ATOMIC_RELAXED, __HIP_MEMORY_SCOPE_AGENT);
        }

        // 4. own-h(t+1) and x(t+1) into next buffer
        if (l == 0) nxt[72 * (q >> 5) + 8 + (q & 31)] = hf;
        if (tid >= 64 && tid < 64 + EMB) {
            int k = tid - 64;
            nxt[72 * (k >> 3) + (k & 7)] = (_Float16)ev;
        }
        barrier_lds();   // A: LDS visibility only, no vmcnt drain

        // 5. issue first partner poll, then own+x dots for step t+1 in its shadow
        unsigned int fdw = 0;
        const unsigned int* psp = part + ps_ * 64;
        if (tid < 64)
            fdw = __hip_atomic_load(psp + tid, __ATOMIC_RELAXED, __HIP_MEMORY_SCOPE_AGENT);

        p0 = 0.f; p1 = 0.f; p2 = 0.f; p3 = 0.f;
        {
            half8_t xv[5];
#pragma unroll
            for (int jj = 0; jj < 5; ++jj)
                xv[jj] = *(const half8_t*)(nxt + 72 * l + 8 * jj);
#pragma unroll
            for (int jj = 0; jj < 5; ++jj) {
                p0 = dot8(w[0][jj], xv[jj], p0);
                p1 = dot8(w[1][jj], xv[jj], p1);
                p2 = dot8(w[2][jj], xv[jj], p2);
                p3 = dot8(w[3][jj], xv[jj], p3);
            }
        }

        // 6. wave0: finish the spin, land partner h(t+1) in next buffer
        if (tid < 64) {
            unsigned int dw = fdw;
            int tries = 0;
            while (!__all(((dw & 1u) == tg) && (((dw >> 16) & 1u) == tg))) {
                if (++tries > (1 << 20)) break;
                __builtin_amdgcn_s_sleep(1);
                dw = __hip_atomic_load(psp + tid, __ATOMIC_RELAXED, __HIP_MEMORY_SCOPE_AGENT);
            }
            unsigned short h0 = (unsigned short)(dw & 0xFFFEu);
            unsigned short h1 = (unsigned short)((dw >> 16) & 0xFFFEu);
            int j0 = 2 * tid, j1 = 2 * tid + 1;
            nxt[72 * (j0 >> 5) + 40 + (j0 & 31)] = __builtin_bit_cast(_Float16, h0);
            nxt[72 * (j1 >> 5) + 40 + (j1 & 31)] = __builtin_bit_cast(_Float16, h1);
        }
        barrier_lds();   // B
    }

    // end handshake: partner done reading my d_out region -> safe to overwrite
    int* ack = (int*)(ws + ACK_OFF);
    if (tid == 0)
        __hip_atomic_store(&ack[bid], L, __ATOMIC_RELEASE, __HIP_MEMORY_SCOPE_AGENT);
    if (tid == 0) {
        int tries = 0;
        while (__hip_atomic_load(&ack[bid ^ 64], __ATOMIC_ACQUIRE, __HIP_MEMORY_SCOPE_AGENT) != L) {
            if (++tries > (1 << 20)) break;
            __builtin_amdgcn_s_sleep(8);
        }
    }
    __syncthreads();
    if (l == 0) out_[(size_t)b * 256 + 128 * role + q] = hh;
}

extern "C" void kernel_launch(void* const* d_in, const int* in_sizes, int n_in,
                              void* d_out, int out_size, void* d_ws, size_t ws_size,
                              hipStream_t stream) {
    const int*   x       = (const int*)d_in[0];
    const int*   lengths = (const int*)d_in[1];
    const float* emb     = (const float*)d_in[2];
    const float* W_ih    = (const float*)d_in[3];
    const float* W_hh    = (const float*)d_in[4];
    const float* b_ih    = (const float*)d_in[5];
    const float* b_hh    = (const float*)d_in[6];

    prep_kernel<<<105, 512, 0, stream>>>(W_ih, W_hh, b_ih, b_hh,
                                         (char*)d_ws, (unsigned int*)d_out);
    rnn_kernel<<<128, 512, 0, stream>>>(x, lengths, emb, (char*)d_ws, (float*)d_out);
}